// Round 5
// baseline (1050.742 us; speedup 1.0000x reference)
//
#include <hip/hip_runtime.h>
#include <hip/hip_cooperative_groups.h>

namespace cg = cooperative_groups;

#define N_NODES 10000
#define N_EDGES 320000
#define BCAP    96      // bucket capacity per (gso,col)
#define NCPY    8       // U/S accumulation copies
#define NCH     64      // edge chunks per gso (== wavefront size, for the shfl scan)
#define HSTRIDE 1280    // hist row stride (1250 cols padded)
#define GRID    512     // cooperative grid: 2 blocks/CU x 256 CUs (2x co-residency margin)
// R5: R4's fused cooperative kernel never RAN (launch rejected at exactly-max
// grid 1024; error code was unchecked -> untouched output: pytest absmax ==
// max|ref|, bench absmax == poison). Fixes:
//   (1) GRID 512 + __launch_bounds__(256,2): co-residency needs only 2
//       blocks/CU (<=256 VGPR, 5KB LDS) - large margin.
//   (2) hipLaunchCooperativeKernel return value checked; on failure, fall
//       back to the harness-verified R3 9-dispatch pipeline (identical math).
// Phase algebra identical to R3 (verified, absmax 9.8e-4):
//   P0 zero | P1 hist | P2 shfl-scan | P3 fill | P4-P6 gstage1-3 | P7 ugemm
//   P8 final_T | P9 final_out. __threadfence() before each grid.sync for
//   cross-XCD L2 visibility of plain stores.

__device__ __forceinline__ unsigned short f2bf(float x) {
    unsigned int u = __float_as_uint(x);
    unsigned int r = (u + 0x7fff + ((u >> 16) & 1)) >> 16;   // RNE
    return (unsigned short)r;
}
__device__ __forceinline__ float bfhi(unsigned int u) { return __uint_as_float(u & 0xffff0000u); }

// ================================================================ fused path
__global__ __launch_bounds__(256, 2) void fused_kernel(
        const float* __restrict__ x, const int* __restrict__ ei,
        const float* __restrict__ ev,
        const float* __restrict__ W1, const float* __restrict__ b1,
        const float* __restrict__ W2, const float* __restrict__ b2,
        float* __restrict__ out,
        unsigned int* __restrict__ bkt, int* __restrict__ hist,
        int* __restrict__ cnt, float* __restrict__ wA,
        float4* __restrict__ wB0, float4* __restrict__ wB1,
        float4* __restrict__ wC0, float4* __restrict__ wC1,
        float* __restrict__ U8, float* __restrict__ S8, float* __restrict__ T) {
    cg::grid_group grid = cg::this_grid();
    __shared__ int sm_i[1280];                  // reused: hist counts / fill bases / src
    float* sm_f = (float*)sm_i;
    int t = threadIdx.x;
    int bid = blockIdx.x;
    const int NB = gridDim.x;
    int gtid = bid * 256 + t;

    // ---------------- P0: zero wA/U8/S8/T/out (cnt,hist fully overwritten later)
    for (int u = gtid; u < 40000 + NCPY * 4096 + NCPY * 4 + 2560 + 512; u += NB * 256) {
        int v = u;
        if (v < 40000) { wA[v] = 0.f; continue; }
        v -= 40000;
        if (v < NCPY * 4096) { U8[v] = 0.f; continue; }
        v -= NCPY * 4096;
        if (v < NCPY * 4) { S8[v] = 0.f; continue; }
        v -= NCPY * 4;
        if (v < 2560) { T[v] = 0.f; continue; }
        v -= 2560;
        out[v] = 0.f;
    }
    // no sync needed before P1: P1 writes hist only (disjoint from P0 targets)

    // ---------------- P1: per-(e,p,chunk) LDS histogram -> hist
    for (int u = bid; u < 2 * NCH * 8; u += NB) {
        int p = u & 7, ec = u >> 3;
        int e = ec / NCH, chunk = ec - e * NCH;
        const int* cp = ei + e * 2 * N_EDGES + N_EDGES + chunk * 5000;
        int clo = p * 1250;
        for (int i = t; i < 1250; i += 256) sm_i[i] = 0;
        __syncthreads();
        for (int i = t; i < 5000; i += 256) {
            int c = cp[i];
            if ((unsigned)(c - clo) < 1250u) atomicAdd(&sm_i[c - clo], 1);
        }
        __syncthreads();
        int* hr = hist + u * HSTRIDE;
        for (int i = t; i < 1250; i += 256) hr[i] = sm_i[i];
        __syncthreads();
    }
    __threadfence(); grid.sync();

    // ---------------- P2: wave-parallel exclusive scan over the 64 chunks per (e,p,ci)
    {
        int wid = gtid >> 6, lane = t & 63;
        int nw = (NB * 256) >> 6;
        for (int u = wid; u < 2 * N_NODES; u += nw) {
            int e = u / N_NODES, rem = u - e * N_NODES;
            int p = rem / 1250, ci = rem - p * 1250;
            int* slot = hist + ((e * NCH + lane) * 8 + p) * HSTRIDE + ci;
            int v = *slot;
            int incl = v;
            #pragma unroll
            for (int d = 1; d < 64; d <<= 1) {
                int nvx = __shfl_up(incl, d);
                if (lane >= d) incl += nvx;
            }
            *slot = incl - v;               // exclusive chunk base
            if (lane == 63) cnt[e * N_NODES + p * 1250 + ci] = incl;
        }
    }
    __threadfence(); grid.sync();

    // ---------------- P3: ranked scatter fill (LDS atomic positions) + wA a1/b1
    for (int u = bid; u < 2 * NCH * 8; u += NB) {
        int p = u & 7, ec = u >> 3;
        int e = ec / NCH, chunk = ec - e * NCH;
        const int* rp = ei + e * 2 * N_EDGES + chunk * 5000;
        const int* cp = rp + N_EDGES;
        const float* vp = ev + e * N_EDGES + chunk * 5000;
        int clo = p * 1250, koff = e ? 2 : 0;
        const int* hr = hist + u * HSTRIDE;
        for (int i = t; i < 1250; i += 256) sm_i[i] = hr[i];
        __syncthreads();
        for (int i = t; i < 5000; i += 256) {
            int c = cp[i];
            if ((unsigned)(c - clo) < 1250u) {
                int r = rp[i];
                float v = vp[i];
                int pos = atomicAdd(&sm_i[c - clo], 1);
                if (pos < BCAP)
                    bkt[(size_t)(e * N_NODES + c) * BCAP + pos] =
                        ((unsigned int)f2bf(v) << 16) | (unsigned int)r;
                if (r == 0) atomicAdd(&wA[c * 4 + koff], v);
            }
        }
        __syncthreads();
    }
    __threadfence(); grid.sync();

    // ---------------- P4: gstage1  a2 = a1*A, b2 = b1*B
    for (int base = bid * 16; base < 2 * N_NODES; base += NB * 16) {
        int gu = base + (t >> 4);
        int li = t & 15;
        if (gu < 2 * N_NODES) {
            int e = (gu >= N_NODES) ? 1 : 0;
            int c = gu - e * N_NODES;
            int nc = cnt[e * N_NODES + c]; if (nc > BCAP) nc = BCAP;
            const unsigned int* bp = bkt + (size_t)(e * N_NODES + c) * BCAP;
            int koff = e ? 2 : 0;
            float acc = 0.f;
            for (int p = li; p < nc; p += 16) {
                unsigned int u = bp[p];
                acc += bfhi(u) * wA[(u & 0xffff) * 4 + koff];
            }
            acc += __shfl_xor(acc, 1); acc += __shfl_xor(acc, 2);
            acc += __shfl_xor(acc, 4); acc += __shfl_xor(acc, 8);
            if (li == 0) wA[c * 4 + koff + 1] = acc;
        }
    }
    __threadfence(); grid.sync();

    // ---------------- P5: gstage2  {c1,d1,e1} / {f1,g1,h1}
    for (int base = bid * 16; base < 2 * N_NODES; base += NB * 16) {
        int gu = base + (t >> 4);
        int li = t & 15;
        if (gu < 2 * N_NODES) {
            int e = (gu >= N_NODES) ? 1 : 0;
            int c = gu - e * N_NODES;
            int nc = cnt[e * N_NODES + c]; if (nc > BCAP) nc = BCAP;
            const unsigned int* bp = bkt + (size_t)(e * N_NODES + c) * BCAP;
            const float4* wAp = (const float4*)wA;
            float x0 = 0.f, x1 = 0.f, x2 = 0.f;
            for (int p = li; p < nc; p += 16) {
                unsigned int u = bp[p];
                float v = bfhi(u);
                float4 wr = wAp[u & 0xffff];
                if (e == 0) { x0 += wr.y * v; x1 += wr.z * v; x2 += wr.w * v; }
                else        { x0 += wr.w * v; x1 += wr.x * v; x2 += wr.y * v; }
            }
            x0 += __shfl_xor(x0, 1); x0 += __shfl_xor(x0, 2); x0 += __shfl_xor(x0, 4); x0 += __shfl_xor(x0, 8);
            x1 += __shfl_xor(x1, 1); x1 += __shfl_xor(x1, 2); x1 += __shfl_xor(x1, 4); x1 += __shfl_xor(x1, 8);
            x2 += __shfl_xor(x2, 1); x2 += __shfl_xor(x2, 2); x2 += __shfl_xor(x2, 4); x2 += __shfl_xor(x2, 8);
            if (li == 0) {
                float4 o = make_float4(x0, x1, x2, 0.f);
                if (e == 0) wB0[c] = o; else wB1[c] = o;
            }
        }
    }
    __threadfence(); grid.sync();

    // ---------------- P6: gstage3  {c1A,d1A,e1A} / {f1B,g1B,h1B}
    for (int base = bid * 16; base < 2 * N_NODES; base += NB * 16) {
        int gu = base + (t >> 4);
        int li = t & 15;
        if (gu < 2 * N_NODES) {
            int e = (gu >= N_NODES) ? 1 : 0;
            int c = gu - e * N_NODES;
            int nc = cnt[e * N_NODES + c]; if (nc > BCAP) nc = BCAP;
            const unsigned int* bp = bkt + (size_t)(e * N_NODES + c) * BCAP;
            const float4* win = e ? wB1 : wB0;
            float x0 = 0.f, x1 = 0.f, x2 = 0.f;
            for (int p = li; p < nc; p += 16) {
                unsigned int u = bp[p];
                float v = bfhi(u);
                float4 wr = win[u & 0xffff];
                x0 += wr.x * v; x1 += wr.y * v; x2 += wr.z * v;
            }
            x0 += __shfl_xor(x0, 1); x0 += __shfl_xor(x0, 2); x0 += __shfl_xor(x0, 4); x0 += __shfl_xor(x0, 8);
            x1 += __shfl_xor(x1, 1); x1 += __shfl_xor(x1, 2); x1 += __shfl_xor(x1, 4); x1 += __shfl_xor(x1, 8);
            x2 += __shfl_xor(x2, 1); x2 += __shfl_xor(x2, 2); x2 += __shfl_xor(x2, 4); x2 += __shfl_xor(x2, 8);
            if (li == 0) {
                float4 o = make_float4(x0, x1, x2, 0.f);
                if (e == 0) wC0[c] = o; else wC1[c] = o;
            }
        }
    }
    __threadfence(); grid.sync();

    // ---------------- P7: U accumulation + base sums
    for (int grp = bid; grp < 625; grp += NB) {
        int b = t >> 6, f = t & 63;
        int n0 = grp * 16;
        int cpy = grp & (NCPY - 1);
        const float* xp = x + b * (N_NODES * 64) + f;
        const float4* wAp = (const float4*)wA;
        float acc[16];
        #pragma unroll
        for (int k = 0; k < 16; ++k) acc[k] = 0.f;
        float s0 = 0.f, s1 = 0.f, s2 = 0.f, s3 = 0.f;
        #pragma unroll
        for (int j = 0; j < 16; ++j) {
            int n = n0 + j;
            float4 a  = wAp[n];
            float4 p0 = wB0[n], p1 = wB1[n];
            float4 q0 = wC0[n], q1 = wC1[n];
            float xv = xp[n * 64];
            acc[0]  += a.x * xv;  acc[1]  += a.y * xv;
            acc[2]  += a.z * xv;  acc[3]  += a.w * xv;
            acc[4]  += p0.x * xv; acc[5]  += p0.y * xv; acc[6]  += p0.z * xv;
            acc[7]  += p1.x * xv; acc[8]  += p1.y * xv; acc[9]  += p1.z * xv;
            acc[10] += q0.x * xv; acc[11] += q0.y * xv; acc[12] += q0.z * xv;
            acc[13] += q1.x * xv; acc[14] += q1.y * xv; acc[15] += q1.z * xv;
            if (t == 0) { s0 += a.x; s1 += a.y; s2 += a.z; s3 += a.w; }
        }
        float* up = U8 + cpy * 4096;
        #pragma unroll
        for (int k = 0; k < 16; ++k)
            atomicAdd(&up[k * 256 + t], acc[k]);
        if (t == 0) {
            float* sp = S8 + cpy * 4;
            atomicAdd(&sp[0], s0); atomicAdd(&sp[1], s1);
            atomicAdd(&sp[2], s2); atomicAdd(&sp[3], s3);
        }
    }
    __threadfence(); grid.sync();

    // ---------------- P8: final stage 1 -> T
    for (int u = bid; u < 25; u += NB) {
        int s = u / 5, g = u - s * 5;
        const int w1off[5] = { 0, 8192, 16384, 32768, 40960 };
        {
            const int hmap[5] = { -1, 0, 1, 2, 3 };
            const int umap[4][5] = {
                { 0, 1, 4,  8, 14 },
                { 1, 4, 10, 9, 15 },
                { 2, 5, 11, 3,  7 },
                { 3, 6, 12, 7, 13 },
            };
            int k = (g == 0) ? hmap[s] : umap[g - 1][s];
            float sv;
            if (k < 0) {
                sv = x[(t >> 6) * (N_NODES * 64) + (t & 63)];
            } else {
                sv = 0.f;
                #pragma unroll
                for (int c = 0; c < NCPY; ++c) sv += U8[c * 4096 + k * 256 + t];
            }
            sm_f[t] = sv;
        }
        __syncthreads();
        int f1 = t & 127, half = t >> 7;
        const float* w1p = W1 + w1off[s];
        float acc0 = 0.f, acc1 = 0.f;
        #pragma unroll 8
        for (int f0 = 0; f0 < 64; ++f0) {
            float w = w1p[f0 * 128 + f1];
            if (s == 0) w += W1[24576 + f0 * 128 + f1];
            acc0 += sm_f[(2 * half) * 64 + f0] * w;
            acc1 += sm_f[(2 * half + 1) * 64 + f0] * w;
        }
        if (s == 0) {
            float bb = b1[f1];
            if (g == 0) { acc0 += bb; acc1 += bb; }
            else {
                float Sg = 0.f;
                #pragma unroll
                for (int c = 0; c < NCPY; ++c) Sg += S8[c * 4 + (g - 1)];
                acc0 += Sg * bb; acc1 += Sg * bb;
            }
        }
        atomicAdd(&T[g * 512 + (2 * half) * 128 + f1], acc0);
        atomicAdd(&T[g * 512 + (2 * half + 1) * 128 + f1], acc1);
        __syncthreads();
    }
    __threadfence(); grid.sync();

    // ---------------- P9: final stage 2 -> out
    for (int g = bid; g < 5; g += NB) {
        const int w2off[5] = { 0, 16384, 32768, 65536, 81920 };
        int f2 = t & 127, half = t >> 7;
        const float* w2p = W2 + w2off[g];
        float acc0 = (g == 0) ? b2[f2] : 0.f;
        float acc1 = acc0;
        #pragma unroll 8
        for (int f1 = 0; f1 < 128; ++f1) {
            float w = w2p[f1 * 128 + f2];
            if (g == 0) w += W2[49152 + f1 * 128 + f2];
            acc0 += T[g * 512 + (2 * half) * 128 + f1] * w;
            acc1 += T[g * 512 + (2 * half + 1) * 128 + f1] * w;
        }
        atomicAdd(&out[(2 * half) * 128 + f2], acc0);
        atomicAdd(&out[(2 * half + 1) * 128 + f2], acc1);
    }
}

// ================================================================ fallback path (verified R3)
__global__ __launch_bounds__(256) void hist_kernel(
        const int* __restrict__ ei, int* __restrict__ hist) {
    __shared__ int h[1250];
    int bid = blockIdx.x;
    int p = bid & 7;
    int ec = bid >> 3;
    int e = ec / NCH, chunk = ec - e * NCH;
    const int* cp = ei + e * 2 * N_EDGES + N_EDGES + chunk * 5000;
    int clo = p * 1250;
    for (int i = threadIdx.x; i < 1250; i += 256) h[i] = 0;
    __syncthreads();
    for (int i = threadIdx.x; i < 5000; i += 256) {
        int c = cp[i];
        if ((unsigned)(c - clo) < 1250u)
            atomicAdd(&h[c - clo], 1);
    }
    __syncthreads();
    int* hr = hist + bid * HSTRIDE;
    for (int i = threadIdx.x; i < 1250; i += 256) hr[i] = h[i];
}

__global__ __launch_bounds__(256) void scan_kernel(
        int* __restrict__ hist, int* __restrict__ cnt) {
    int u = blockIdx.x * 256 + threadIdx.x;
    if (u >= 2 * N_NODES) return;
    int e = u / N_NODES;
    int rem = u - e * N_NODES;
    int p = rem / 1250, ci = rem - p * 1250;
    int run = 0;
    #pragma unroll
    for (int k = 0; k < NCH; ++k) {
        int* slot = hist + ((e * NCH + k) * 8 + p) * HSTRIDE + ci;
        int v = *slot;
        *slot = run;
        run += v;
    }
    cnt[e * N_NODES + p * 1250 + ci] = run;
}

__global__ __launch_bounds__(256) void fill_kernel(
        const int* __restrict__ ei, const float* __restrict__ ev,
        const int* __restrict__ hist, unsigned int* __restrict__ bkt,
        float* __restrict__ wA) {
    __shared__ int base_l[1250];
    int bid = blockIdx.x;
    int p = bid & 7;
    int ec = bid >> 3;
    int e = ec / NCH, chunk = ec - e * NCH;
    const int* rp = ei + e * 2 * N_EDGES + chunk * 5000;
    const int* cp = rp + N_EDGES;
    const float* vp = ev + e * N_EDGES + chunk * 5000;
    int clo = p * 1250;
    int koff = e ? 2 : 0;
    const int* hr = hist + bid * HSTRIDE;
    for (int i = threadIdx.x; i < 1250; i += 256) base_l[i] = hr[i];
    __syncthreads();
    for (int i = threadIdx.x; i < 5000; i += 256) {
        int c = cp[i];
        if ((unsigned)(c - clo) < 1250u) {
            int r = rp[i];
            float v = vp[i];
            int pos = atomicAdd(&base_l[c - clo], 1);
            if (pos < BCAP)
                bkt[(e * N_NODES + c) * BCAP + pos] = ((unsigned int)f2bf(v) << 16) | (unsigned int)r;
            if (r == 0)
                atomicAdd(&wA[c * 4 + koff], v);
        }
    }
}

__global__ __launch_bounds__(256) void gstage1_kernel(
        const unsigned int* __restrict__ bkt, const int* __restrict__ cnt,
        float* __restrict__ wA) {
    int t = threadIdx.x;
    int gu = (blockIdx.x << 4) + (t >> 4);
    int li = t & 15;
    int e = (gu >= N_NODES) ? 1 : 0;
    int c = gu - e * N_NODES;
    int nc = cnt[e * N_NODES + c]; if (nc > BCAP) nc = BCAP;
    const unsigned int* bp = bkt + (e * N_NODES + c) * BCAP;
    int koff = e ? 2 : 0;
    float acc = 0.f;
    for (int p = li; p < nc; p += 16) {
        unsigned int u = bp[p];
        acc += bfhi(u) * wA[(u & 0xffff) * 4 + koff];
    }
    acc += __shfl_xor(acc, 1); acc += __shfl_xor(acc, 2);
    acc += __shfl_xor(acc, 4); acc += __shfl_xor(acc, 8);
    if (li == 0) wA[c * 4 + koff + 1] = acc;
}

__global__ __launch_bounds__(256) void gstage2_kernel(
        const unsigned int* __restrict__ bkt, const int* __restrict__ cnt,
        const float* __restrict__ wA, float4* __restrict__ wB0, float4* __restrict__ wB1) {
    int t = threadIdx.x;
    int gu = (blockIdx.x << 4) + (t >> 4);
    int li = t & 15;
    int e = (gu >= N_NODES) ? 1 : 0;
    int c = gu - e * N_NODES;
    int nc = cnt[e * N_NODES + c]; if (nc > BCAP) nc = BCAP;
    const unsigned int* bp = bkt + (e * N_NODES + c) * BCAP;
    const float4* wAp = (const float4*)wA;
    float x0 = 0.f, x1 = 0.f, x2 = 0.f;
    for (int p = li; p < nc; p += 16) {
        unsigned int u = bp[p];
        float v = bfhi(u);
        float4 wr = wAp[u & 0xffff];
        if (e == 0) { x0 += wr.y * v; x1 += wr.z * v; x2 += wr.w * v; }
        else        { x0 += wr.w * v; x1 += wr.x * v; x2 += wr.y * v; }
    }
    x0 += __shfl_xor(x0, 1); x0 += __shfl_xor(x0, 2); x0 += __shfl_xor(x0, 4); x0 += __shfl_xor(x0, 8);
    x1 += __shfl_xor(x1, 1); x1 += __shfl_xor(x1, 2); x1 += __shfl_xor(x1, 4); x1 += __shfl_xor(x1, 8);
    x2 += __shfl_xor(x2, 1); x2 += __shfl_xor(x2, 2); x2 += __shfl_xor(x2, 4); x2 += __shfl_xor(x2, 8);
    if (li == 0) {
        float4 o = make_float4(x0, x1, x2, 0.f);
        if (e == 0) wB0[c] = o; else wB1[c] = o;
    }
}

__global__ __launch_bounds__(256) void gstage3_kernel(
        const unsigned int* __restrict__ bkt, const int* __restrict__ cnt,
        const float4* __restrict__ wB0, const float4* __restrict__ wB1,
        float4* __restrict__ wC0, float4* __restrict__ wC1) {
    int t = threadIdx.x;
    int gu = (blockIdx.x << 4) + (t >> 4);
    int li = t & 15;
    int e = (gu >= N_NODES) ? 1 : 0;
    int c = gu - e * N_NODES;
    int nc = cnt[e * N_NODES + c]; if (nc > BCAP) nc = BCAP;
    const unsigned int* bp = bkt + (e * N_NODES + c) * BCAP;
    const float4* win = e ? wB1 : wB0;
    float x0 = 0.f, x1 = 0.f, x2 = 0.f;
    for (int p = li; p < nc; p += 16) {
        unsigned int u = bp[p];
        float v = bfhi(u);
        float4 wr = win[u & 0xffff];
        x0 += wr.x * v; x1 += wr.y * v; x2 += wr.z * v;
    }
    x0 += __shfl_xor(x0, 1); x0 += __shfl_xor(x0, 2); x0 += __shfl_xor(x0, 4); x0 += __shfl_xor(x0, 8);
    x1 += __shfl_xor(x1, 1); x1 += __shfl_xor(x1, 2); x1 += __shfl_xor(x1, 4); x1 += __shfl_xor(x1, 8);
    x2 += __shfl_xor(x2, 1); x2 += __shfl_xor(x2, 2); x2 += __shfl_xor(x2, 4); x2 += __shfl_xor(x2, 8);
    if (li == 0) {
        float4 o = make_float4(x0, x1, x2, 0.f);
        if (e == 0) wC0[c] = o; else wC1[c] = o;
    }
}

__global__ __launch_bounds__(256) void ugemm_kernel(const float* __restrict__ x,
                                                    const float* __restrict__ wA,
                                                    const float4* __restrict__ wB0,
                                                    const float4* __restrict__ wB1,
                                                    const float4* __restrict__ wC0,
                                                    const float4* __restrict__ wC1,
                                                    float* __restrict__ U8,
                                                    float* __restrict__ S8) {
    int t = threadIdx.x;
    int b = t >> 6, f = t & 63;
    int n0 = blockIdx.x * 16;
    int cp = blockIdx.x & (NCPY - 1);
    const float* xp = x + b * (N_NODES * 64) + f;
    const float4* wAp = (const float4*)wA;
    float acc[16];
    #pragma unroll
    for (int k = 0; k < 16; ++k) acc[k] = 0.f;
    float s0 = 0.f, s1 = 0.f, s2 = 0.f, s3 = 0.f;
    #pragma unroll
    for (int j = 0; j < 16; ++j) {
        int n = n0 + j;
        float4 a  = wAp[n];
        float4 p0 = wB0[n], p1 = wB1[n];
        float4 q0 = wC0[n], q1 = wC1[n];
        float xv = xp[n * 64];
        acc[0]  += a.x * xv;  acc[1]  += a.y * xv;
        acc[2]  += a.z * xv;  acc[3]  += a.w * xv;
        acc[4]  += p0.x * xv; acc[5]  += p0.y * xv; acc[6]  += p0.z * xv;
        acc[7]  += p1.x * xv; acc[8]  += p1.y * xv; acc[9]  += p1.z * xv;
        acc[10] += q0.x * xv; acc[11] += q0.y * xv; acc[12] += q0.z * xv;
        acc[13] += q1.x * xv; acc[14] += q1.y * xv; acc[15] += q1.z * xv;
        if (t == 0) { s0 += a.x; s1 += a.y; s2 += a.z; s3 += a.w; }
    }
    float* up = U8 + cp * 4096;
    #pragma unroll
    for (int k = 0; k < 16; ++k)
        atomicAdd(&up[k * 256 + t], acc[k]);
    if (t == 0) {
        float* sp = S8 + cp * 4;
        atomicAdd(&sp[0], s0); atomicAdd(&sp[1], s1);
        atomicAdd(&sp[2], s2); atomicAdd(&sp[3], s3);
    }
}

__global__ __launch_bounds__(512) void final_T_kernel(
        const float* __restrict__ x, const float* __restrict__ U8,
        const float* __restrict__ S8,
        const float* __restrict__ W1, const float* __restrict__ b1,
        float* __restrict__ T, float* __restrict__ out) {
    __shared__ float Ws[8192];
    __shared__ float src[256];
    int blk = blockIdx.x;
    int s = blk / 5, g = blk - s * 5;
    int t = threadIdx.x;
    if (blk == 0) out[t] = 0.f;
    const int w1off[5] = { 0, 8192, 16384, 32768, 40960 };
    const float4* wsrc = (const float4*)(W1 + w1off[s]);
    const float4* wsrc0 = (const float4*)(W1 + 24576);
    float4* wdst = (float4*)Ws;
    #pragma unroll
    for (int i = 0; i < 4; ++i) {
        float4 v = wsrc[i * 512 + t];
        if (s == 0) {
            float4 v2 = wsrc0[i * 512 + t];
            v.x += v2.x; v.y += v2.y; v.z += v2.z; v.w += v2.w;
        }
        wdst[i * 512 + t] = v;
    }
    if (t < 256) {
        const int hmap[5] = { -1, 0, 1, 2, 3 };
        const int umap[4][5] = {
            { 0, 1, 4,  8, 14 },
            { 1, 4, 10, 9, 15 },
            { 2, 5, 11, 3,  7 },
            { 3, 6, 12, 7, 13 },
        };
        int k = (g == 0) ? hmap[s] : umap[g - 1][s];
        float sv;
        if (k < 0) {
            sv = x[(t >> 6) * (N_NODES * 64) + (t & 63)];
        } else {
            sv = 0.f;
            #pragma unroll
            for (int c = 0; c < NCPY; ++c) sv += U8[c * 4096 + k * 256 + t];
        }
        src[t] = sv;
    }
    __syncthreads();
    int b = t >> 7, f1 = t & 127;
    const float* sp = src + b * 64;
    float acc = 0.f;
    #pragma unroll 16
    for (int f0 = 0; f0 < 64; ++f0)
        acc += sp[f0] * Ws[f0 * 128 + f1];
    if (s == 0) {
        if (g == 0) acc += b1[f1];
        else {
            float Sg = 0.f;
            #pragma unroll
            for (int c = 0; c < NCPY; ++c) Sg += S8[c * 4 + (g - 1)];
            acc += Sg * b1[f1];
        }
    }
    atomicAdd(&T[g * 512 + t], acc);
}

__global__ __launch_bounds__(512) void final_out_kernel(
        const float* __restrict__ T, const float* __restrict__ W2,
        const float* __restrict__ b2, float* __restrict__ out) {
    __shared__ float Ws[16384];
    __shared__ float Ts[512];
    int g = blockIdx.x;
    int t = threadIdx.x;
    const int w2off[5] = { 0, 16384, 32768, 65536, 81920 };
    const float4* wsrc = (const float4*)(W2 + w2off[g]);
    const float4* wsrc0 = (const float4*)(W2 + 49152);
    float4* wdst = (float4*)Ws;
    #pragma unroll
    for (int i = 0; i < 8; ++i) {
        float4 v = wsrc[i * 512 + t];
        if (g == 0) {
            float4 v2 = wsrc0[i * 512 + t];
            v.x += v2.x; v.y += v2.y; v.z += v2.z; v.w += v2.w;
        }
        wdst[i * 512 + t] = v;
    }
    Ts[t] = T[g * 512 + t];
    __syncthreads();
    int b = t >> 7, f2 = t & 127;
    const float* tp = Ts + b * 128;
    float acc = (g == 0) ? b2[f2] : 0.f;
    #pragma unroll 16
    for (int f1 = 0; f1 < 128; ++f1)
        acc += tp[f1] * Ws[f1 * 128 + f2];
    atomicAdd(&out[t], acc);
}

// ----------------------------------------------------------------
extern "C" void kernel_launch(void* const* d_in, const int* in_sizes, int n_in,
                              void* d_out, int out_size, void* d_ws, size_t ws_size,
                              hipStream_t stream) {
    const float* x  = (const float*)d_in[0];
    const int*   ei = (const int*)d_in[1];
    const float* ev = (const float*)d_in[2];
    const float* W1 = (const float*)d_in[3];
    const float* b1 = (const float*)d_in[4];
    const float* W2 = (const float*)d_in[5];
    const float* b2 = (const float*)d_in[6];
    float* out = (float*)d_out;

    char* ws = (char*)d_ws;
    size_t off = 0;
    auto alloc = [&](size_t bytes) { size_t o = off; off += (bytes + 255) & ~(size_t)255; return o; };
    size_t o_bkt   = alloc((size_t)2 * N_NODES * BCAP * 4);    // 7.7 MB buckets
    size_t o_hist  = alloc((size_t)2 * NCH * 8 * HSTRIDE * 4); // 5.2 MB chunk hists
    size_t o_zero  = off;                                      // fallback-zeroed region
    size_t o_cnt   = alloc((size_t)2 * N_NODES * 4);
    size_t o_wA    = alloc((size_t)N_NODES * 4 * 4);
    size_t o_wB0   = alloc((size_t)N_NODES * 4 * 4);
    size_t o_wB1   = alloc((size_t)N_NODES * 4 * 4);
    size_t o_wC0   = alloc((size_t)N_NODES * 4 * 4);
    size_t o_wC1   = alloc((size_t)N_NODES * 4 * 4);
    size_t o_U     = alloc((size_t)NCPY * 16 * 256 * 4);
    size_t o_S     = alloc((size_t)NCPY * 4 * 4);
    size_t o_T     = alloc((size_t)5 * 512 * 4);
    size_t zero_bytes = off - o_zero;

    unsigned int* bkt = (unsigned int*)(ws + o_bkt);
    int*    hist  = (int*)(ws + o_hist);
    int*    cnt   = (int*)(ws + o_cnt);
    float*  wA    = (float*)(ws + o_wA);
    float4* wB0   = (float4*)(ws + o_wB0);
    float4* wB1   = (float4*)(ws + o_wB1);
    float4* wC0   = (float4*)(ws + o_wC0);
    float4* wC1   = (float4*)(ws + o_wC1);
    float*  U8    = (float*)(ws + o_U);
    float*  S8    = (float*)(ws + o_S);
    float*  T     = (float*)(ws + o_T);

    void* args[] = { &x, &ei, &ev, &W1, &b1, &W2, &b2, &out,
                     &bkt, &hist, &cnt, &wA, &wB0, &wB1, &wC0, &wC1,
                     &U8, &S8, &T };
    hipError_t st = hipLaunchCooperativeKernel((const void*)fused_kernel,
                                               dim3(GRID), dim3(256), args, 0, stream);
    if (st != hipSuccess) {
        // verified R3 multi-kernel fallback
        hipMemsetAsync(ws + o_zero, 0, zero_bytes, stream);
        hist_kernel    <<<2 * NCH * 8, 256, 0, stream>>>(ei, hist);
        scan_kernel    <<<80,   256, 0, stream>>>(hist, cnt);
        fill_kernel    <<<2 * NCH * 8, 256, 0, stream>>>(ei, ev, hist, bkt, wA);
        gstage1_kernel <<<1250, 256, 0, stream>>>(bkt, cnt, wA);
        gstage2_kernel <<<1250, 256, 0, stream>>>(bkt, cnt, wA, wB0, wB1);
        gstage3_kernel <<<1250, 256, 0, stream>>>(bkt, cnt, wB0, wB1, wC0, wC1);
        ugemm_kernel   <<<625,  256, 0, stream>>>(x, wA, wB0, wB1, wC0, wC1, U8, S8);
        final_T_kernel <<<25,   512, 0, stream>>>(x, U8, S8, W1, b1, T, out);
        final_out_kernel<<<5,   512, 0, stream>>>(T, W2, b2, out);
    }
}

// Round 6
// 156.070 us; speedup vs baseline: 6.7325x; 6.7325x over previous
//
#include <hip/hip_runtime.h>

#define N_NODES 10000
#define N_EDGES 320000
#define BCAP    96      // bucket capacity per (gso,col); deg ~ Poisson(32), +11 sigma
#define NCPY    8       // U/S accumulation copies
#define UNODES  80      // nodes per ugemm block (R6: was 16)
#define UBLKS   125     // 125*80 = 10000 exactly (R6: was 625)
// Backward-functional formulation, gather propagation over single-pass
// fixed-capacity column buckets (no prefix/scatter):
//   bucket[(e,c)] holds packed (bf16(v)<<16 | row) for all edges (r,c,v) of gso e
//   w_out[c] = sum_p w_in[row_p] * v_p         (no atomics in stages)
// Vectors (A = S0, B = S1, right-multiplication of row functionals):
//   wA  [n]: {a1=e0A, a2=e0A^2, b1=e0B, b2=e0B^2}
//   wB0 [n]: {c1=a2A, d1=b1A, e1=b2A, -}       (stage2 via buckets e=0)
//   wB1 [n]: {f1=b2B, g1=a1B, h1=a2B, -}       (stage2 via buckets e=1)
//   wC0 [n]: {c1A, d1A, e1A, -}                (stage3 via buckets e=0)
//   wC1 [n]: {f1B, g1B, h1B, -}                (stage3 via buckets e=1)
//
// R5 lesson (measured): grid.sync() cooperative fusion = 1010us vs 159us —
// every sync is a cross-XCD L2 writeback/invalidate + cold-cache restart
// (FETCH 74MB vs ~40MB, VALUBusy 0.9%). Multi-kernel dispatch boundaries are
// the CHEAP way to get cross-XCD coherence. Fusion abandoned.
// R6 change (single variable vs R2): ugemm only — 625x16 -> 125x80 blocks,
// global atomicAdds 2.56M -> 512K (5x), probing the atomic-throughput theory.

__device__ __forceinline__ unsigned short f2bf(float x) {
    unsigned int u = __float_as_uint(x);
    unsigned int r = (u + 0x7fff + ((u >> 16) & 1)) >> 16;   // RNE
    return (unsigned short)r;
}
__device__ __forceinline__ float bfhi(unsigned int u) { return __uint_as_float(u & 0xffff0000u); }

// ---------------------------------------------------------------- pass 1: bucket build + stage0
// 2048 blocks = 8 partitions x 256 chunks of 2500 edges (256*2500 = 640000;
// chunks never straddle the gso boundary since 320000 = 128*2500).
__global__ __launch_bounds__(256) void bucket_kernel(
        const int* __restrict__ ei, const float* __restrict__ ev,
        int* __restrict__ cnt, unsigned int* __restrict__ bkt,
        float* __restrict__ wA) {
    int part  = blockIdx.x & 7;                 // presumed XCD id
    int chunk = blockIdx.x >> 3;                // 0..255
    int base  = chunk * 2500;
    int e  = (base >= N_EDGES) ? 1 : 0;         // uniform per block
    int t0 = base - e * N_EDGES;
    const int*   rp = ei + e * 2 * N_EDGES;
    const int*   cp = rp + N_EDGES;
    const float* vp = ev + e * N_EDGES;
    int clo = part * 1250;
    int koff = e ? 2 : 0;
    for (int i = threadIdx.x; i < 2500; i += 256) {
        int t = t0 + i;
        int c = cp[t];                          // coalesced; L3-resident on re-reads
        if ((unsigned)(c - clo) < 1250u) {      // my column partition only
            int r = rp[t];
            float v = vp[t];
            int pos = atomicAdd(&cnt[e * N_NODES + c], 1);
            if (pos < BCAP)
                bkt[(e * N_NODES + c) * BCAP + pos] = ((unsigned int)f2bf(v) << 16) | (unsigned int)r;
            if (r == 0)   // a1[c] += v (gso0) / b1[c] += v (gso1)
                atomicAdd(&wA[c * 4 + koff], v);
        }
    }
}

// ---------------------------------------------------------------- stage 1: a2 = a1*A, b2 = b1*B
// 16-lane unit per (gso, col); gather over bucket; one coalesced store.
__global__ __launch_bounds__(256) void gstage1_kernel(
        const unsigned int* __restrict__ bkt, const int* __restrict__ cnt,
        float* __restrict__ wA) {
    int t = threadIdx.x;
    int gu = (blockIdx.x << 4) + (t >> 4);
    int li = t & 15;
    int e = (gu >= N_NODES) ? 1 : 0;
    int c = gu - e * N_NODES;
    int nc = cnt[e * N_NODES + c]; if (nc > BCAP) nc = BCAP;
    const unsigned int* bp = bkt + (e * N_NODES + c) * BCAP;
    int koff = e ? 2 : 0;
    float acc = 0.f;
    for (int p = li; p < nc; p += 16) {
        unsigned int u = bp[p];
        acc += bfhi(u) * wA[(u & 0xffff) * 4 + koff];   // reads .x/.z only, writes .y/.w
    }
    acc += __shfl_xor(acc, 1); acc += __shfl_xor(acc, 2);
    acc += __shfl_xor(acc, 4); acc += __shfl_xor(acc, 8);
    if (li == 0) wA[c * 4 + koff + 1] = acc;
}

// ---------------------------------------------------------------- stage 2: {c1,d1,e1} / {f1,g1,h1}
__global__ __launch_bounds__(256) void gstage2_kernel(
        const unsigned int* __restrict__ bkt, const int* __restrict__ cnt,
        const float* __restrict__ wA, float4* __restrict__ wB0, float4* __restrict__ wB1) {
    int t = threadIdx.x;
    int gu = (blockIdx.x << 4) + (t >> 4);
    int li = t & 15;
    int e = (gu >= N_NODES) ? 1 : 0;
    int c = gu - e * N_NODES;
    int nc = cnt[e * N_NODES + c]; if (nc > BCAP) nc = BCAP;
    const unsigned int* bp = bkt + (e * N_NODES + c) * BCAP;
    const float4* wAp = (const float4*)wA;
    float x0 = 0.f, x1 = 0.f, x2 = 0.f;
    for (int p = li; p < nc; p += 16) {
        unsigned int u = bp[p];
        float v = bfhi(u);
        float4 wr = wAp[u & 0xffff];
        if (e == 0) { x0 += wr.y * v; x1 += wr.z * v; x2 += wr.w * v; }  // c1=a2A, d1=b1A, e1=b2A
        else        { x0 += wr.w * v; x1 += wr.x * v; x2 += wr.y * v; }  // f1=b2B, g1=a1B, h1=a2B
    }
    x0 += __shfl_xor(x0, 1); x0 += __shfl_xor(x0, 2); x0 += __shfl_xor(x0, 4); x0 += __shfl_xor(x0, 8);
    x1 += __shfl_xor(x1, 1); x1 += __shfl_xor(x1, 2); x1 += __shfl_xor(x1, 4); x1 += __shfl_xor(x1, 8);
    x2 += __shfl_xor(x2, 1); x2 += __shfl_xor(x2, 2); x2 += __shfl_xor(x2, 4); x2 += __shfl_xor(x2, 8);
    if (li == 0) {
        float4 o = make_float4(x0, x1, x2, 0.f);
        if (e == 0) wB0[c] = o; else wB1[c] = o;
    }
}

// ---------------------------------------------------------------- stage 3: {c1A,d1A,e1A} / {f1B,g1B,h1B}
__global__ __launch_bounds__(256) void gstage3_kernel(
        const unsigned int* __restrict__ bkt, const int* __restrict__ cnt,
        const float4* __restrict__ wB0, const float4* __restrict__ wB1,
        float4* __restrict__ wC0, float4* __restrict__ wC1) {
    int t = threadIdx.x;
    int gu = (blockIdx.x << 4) + (t >> 4);
    int li = t & 15;
    int e = (gu >= N_NODES) ? 1 : 0;
    int c = gu - e * N_NODES;
    int nc = cnt[e * N_NODES + c]; if (nc > BCAP) nc = BCAP;
    const unsigned int* bp = bkt + (e * N_NODES + c) * BCAP;
    const float4* win = e ? wB1 : wB0;
    float x0 = 0.f, x1 = 0.f, x2 = 0.f;
    for (int p = li; p < nc; p += 16) {
        unsigned int u = bp[p];
        float v = bfhi(u);
        float4 wr = win[u & 0xffff];
        x0 += wr.x * v; x1 += wr.y * v; x2 += wr.z * v;
    }
    x0 += __shfl_xor(x0, 1); x0 += __shfl_xor(x0, 2); x0 += __shfl_xor(x0, 4); x0 += __shfl_xor(x0, 8);
    x1 += __shfl_xor(x1, 1); x1 += __shfl_xor(x1, 2); x1 += __shfl_xor(x1, 4); x1 += __shfl_xor(x1, 8);
    x2 += __shfl_xor(x2, 1); x2 += __shfl_xor(x2, 2); x2 += __shfl_xor(x2, 4); x2 += __shfl_xor(x2, 8);
    if (li == 0) {
        float4 o = make_float4(x0, x1, x2, 0.f);
        if (e == 0) wC0[c] = o; else wC1[c] = o;
    }
}

// ---------------------------------------------------------------- U accumulation + base sums
// R6: 125 blocks x 256 thr; block = 80 consecutive nodes (#pragma unroll 8:
// ~40 independent loads in flight). Atomic count 2.56M -> 512K (5x), spread
// over NCPY copies (contention ~15.6 per address).
__global__ __launch_bounds__(256) void ugemm_kernel(const float* __restrict__ x,
                                                    const float* __restrict__ wA,
                                                    const float4* __restrict__ wB0,
                                                    const float4* __restrict__ wB1,
                                                    const float4* __restrict__ wC0,
                                                    const float4* __restrict__ wC1,
                                                    float* __restrict__ U8,
                                                    float* __restrict__ S8) {
    int t = threadIdx.x;
    int b = t >> 6, f = t & 63;
    int n0 = blockIdx.x * UNODES;                 // 125*80 = 10000 exactly
    int cp = blockIdx.x & (NCPY - 1);
    const float* xp = x + b * (N_NODES * 64) + f;
    const float4* wAp = (const float4*)wA;
    float acc[16];
    #pragma unroll
    for (int k = 0; k < 16; ++k) acc[k] = 0.f;
    float s0 = 0.f, s1 = 0.f, s2 = 0.f, s3 = 0.f;
    #pragma unroll 8
    for (int j = 0; j < UNODES; ++j) {
        int n = n0 + j;
        float4 a  = wAp[n];
        float4 p0 = wB0[n], p1 = wB1[n];
        float4 q0 = wC0[n], q1 = wC1[n];
        float xv = xp[n * 64];
        acc[0]  += a.x * xv;  acc[1]  += a.y * xv;
        acc[2]  += a.z * xv;  acc[3]  += a.w * xv;
        acc[4]  += p0.x * xv; acc[5]  += p0.y * xv; acc[6]  += p0.z * xv;
        acc[7]  += p1.x * xv; acc[8]  += p1.y * xv; acc[9]  += p1.z * xv;
        acc[10] += q0.x * xv; acc[11] += q0.y * xv; acc[12] += q0.z * xv;
        acc[13] += q1.x * xv; acc[14] += q1.y * xv; acc[15] += q1.z * xv;
        if (t == 0) { s0 += a.x; s1 += a.y; s2 += a.z; s3 += a.w; }
    }
    float* up = U8 + cp * 4096;
    #pragma unroll
    for (int k = 0; k < 16; ++k)
        atomicAdd(&up[k * 256 + t], acc[k]);
    if (t == 0) {
        float* sp = S8 + cp * 4;
        atomicAdd(&sp[0], s0); atomicAdd(&sp[1], s1);
        atomicAdd(&sp[2], s2); atomicAdd(&sp[3], s3);
    }
}

// ---------------------------------------------------------------- final stage 1
// block = (s,g), 25 blocks x 512 thr. W1c_s (32 KB) in LDS; src = U[k] (folded
// over the NCPY copies) or x node 0. Block 0 zeroes out[512].
// U k-slots: 0-3 a1,a2,b1,b2; 4-6 c1,d1,e1; 7-9 f1,g1,h1; 10-12 c1A,d1A,e1A; 13-15 f1B,g1B,h1B.
__global__ __launch_bounds__(512) void final_T_kernel(
        const float* __restrict__ x, const float* __restrict__ U8,
        const float* __restrict__ S8,
        const float* __restrict__ W1, const float* __restrict__ b1,
        float* __restrict__ T, float* __restrict__ out) {
    __shared__ float Ws[8192];     // 32 KB: W1c_s[f0][f1]
    __shared__ float src[256];
    int blk = blockIdx.x;
    int s = blk / 5, g = blk - s * 5;
    int t = threadIdx.x;
    if (blk == 0) out[t] = 0.f;
    const int w1off[5] = { 0, 8192, 16384, 32768, 40960 };
    const float4* wsrc = (const float4*)(W1 + w1off[s]);
    const float4* wsrc0 = (const float4*)(W1 + 24576);     // W1[1,0], added when s==0
    float4* wdst = (float4*)Ws;
    #pragma unroll
    for (int i = 0; i < 4; ++i) {
        float4 v = wsrc[i * 512 + t];
        if (s == 0) {
            float4 v2 = wsrc0[i * 512 + t];
            v.x += v2.x; v.y += v2.y; v.z += v2.z; v.w += v2.w;
        }
        wdst[i * 512 + t] = v;
    }
    if (t < 256) {
        const int hmap[5] = { -1, 0, 1, 2, 3 };   // z_s[0]: x0, a1, a2, b1, b2
        const int umap[4][5] = {
            { 0, 1, 4,  8, 14 },   // ek0=a1: a1, a2, c1,  g1,  g1B
            { 1, 4, 10, 9, 15 },   // ek1=a2: a2, c1, c1A, h1,  h1B
            { 2, 5, 11, 3,  7 },   // ek2=b1: b1, d1, d1A, b2,  f1
            { 3, 6, 12, 7, 13 },   // ek3=b2: b2, e1, e1A, f1,  f1B
        };
        int k = (g == 0) ? hmap[s] : umap[g - 1][s];
        float sv;
        if (k < 0) {
            sv = x[(t >> 6) * (N_NODES * 64) + (t & 63)];  // x[b][0][f]
        } else {
            sv = 0.f;
            #pragma unroll
            for (int c = 0; c < NCPY; ++c) sv += U8[c * 4096 + k * 256 + t];
        }
        src[t] = sv;
    }
    __syncthreads();
    int b = t >> 7, f1 = t & 127;
    const float* sp = src + b * 64;
    float acc = 0.f;
    #pragma unroll 16
    for (int f0 = 0; f0 < 64; ++f0)
        acc += sp[f0] * Ws[f0 * 128 + f1];
    if (s == 0) {
        if (g == 0) acc += b1[f1];
        else {
            float Sg = 0.f;
            #pragma unroll
            for (int c = 0; c < NCPY; ++c) Sg += S8[c * 4 + (g - 1)];
            acc += Sg * b1[f1];
        }
    }
    atomicAdd(&T[g * 512 + t], acc);
}

// ---------------------------------------------------------------- final stage 2
__global__ __launch_bounds__(512) void final_out_kernel(
        const float* __restrict__ T, const float* __restrict__ W2,
        const float* __restrict__ b2, float* __restrict__ out) {
    __shared__ float Ws[16384];    // 64 KB: W2c_g[f1][f2]
    __shared__ float Ts[512];
    int g = blockIdx.x;
    int t = threadIdx.x;
    const int w2off[5] = { 0, 16384, 32768, 65536, 81920 };  // W2[00],[01],[02],[11],[12]
    const float4* wsrc = (const float4*)(W2 + w2off[g]);
    const float4* wsrc0 = (const float4*)(W2 + 49152);       // W2[1,0], added when g==0
    float4* wdst = (float4*)Ws;
    #pragma unroll
    for (int i = 0; i < 8; ++i) {
        float4 v = wsrc[i * 512 + t];
        if (g == 0) {
            float4 v2 = wsrc0[i * 512 + t];
            v.x += v2.x; v.y += v2.y; v.z += v2.z; v.w += v2.w;
        }
        wdst[i * 512 + t] = v;
    }
    Ts[t] = T[g * 512 + t];
    __syncthreads();
    int b = t >> 7, f2 = t & 127;
    const float* tp = Ts + b * 128;
    float acc = (g == 0) ? b2[f2] : 0.f;
    #pragma unroll 16
    for (int f1 = 0; f1 < 128; ++f1)
        acc += tp[f1] * Ws[f1 * 128 + f2];
    atomicAdd(&out[t], acc);
}

// ----------------------------------------------------------------
extern "C" void kernel_launch(void* const* d_in, const int* in_sizes, int n_in,
                              void* d_out, int out_size, void* d_ws, size_t ws_size,
                              hipStream_t stream) {
    const float* x  = (const float*)d_in[0];
    const int*   ei = (const int*)d_in[1];
    const float* ev = (const float*)d_in[2];
    const float* W1 = (const float*)d_in[3];
    const float* b1 = (const float*)d_in[4];
    const float* W2 = (const float*)d_in[5];
    const float* b2 = (const float*)d_in[6];
    float* out = (float*)d_out;

    char* ws = (char*)d_ws;
    size_t off = 0;
    auto alloc = [&](size_t bytes) { size_t o = off; off += (bytes + 255) & ~(size_t)255; return o; };
    size_t o_bkt   = alloc((size_t)2 * N_NODES * BCAP * 4);   // 7.7 MB buckets (cnt-bounded)
    size_t o_zero  = off;                                     // zeroed region starts here
    size_t o_cnt   = alloc((size_t)2 * N_NODES * 4);
    size_t o_wA    = alloc((size_t)N_NODES * 4 * 4);          // {a1,a2,b1,b2}
    size_t o_wB0   = alloc((size_t)N_NODES * 4 * 4);          // {c1,d1,e1,-}
    size_t o_wB1   = alloc((size_t)N_NODES * 4 * 4);          // {f1,g1,h1,-}
    size_t o_wC0   = alloc((size_t)N_NODES * 4 * 4);          // {c1A,d1A,e1A,-}
    size_t o_wC1   = alloc((size_t)N_NODES * 4 * 4);          // {f1B,g1B,h1B,-}
    size_t o_U     = alloc((size_t)NCPY * 16 * 256 * 4);      // U copies (atomic-accumulated)
    size_t o_S     = alloc((size_t)NCPY * 4 * 4);
    size_t o_T     = alloc((size_t)5 * 512 * 4);
    size_t zero_bytes = off - o_zero;

    unsigned int* bkt = (unsigned int*)(ws + o_bkt);
    int*    cnt   = (int*)(ws + o_cnt);
    float*  wA    = (float*)(ws + o_wA);
    float4* wB0   = (float4*)(ws + o_wB0);
    float4* wB1   = (float4*)(ws + o_wB1);
    float4* wC0   = (float4*)(ws + o_wC0);
    float4* wC1   = (float4*)(ws + o_wC1);
    float*  U8    = (float*)(ws + o_U);
    float*  S8    = (float*)(ws + o_S);
    float*  T     = (float*)(ws + o_T);

    hipMemsetAsync(ws + o_zero, 0, zero_bytes, stream);

    bucket_kernel  <<<2048, 256, 0, stream>>>(ei, ev, cnt, bkt, wA);
    gstage1_kernel <<<1250, 256, 0, stream>>>(bkt, cnt, wA);
    gstage2_kernel <<<1250, 256, 0, stream>>>(bkt, cnt, wA, wB0, wB1);
    gstage3_kernel <<<1250, 256, 0, stream>>>(bkt, cnt, wB0, wB1, wC0, wC1);
    ugemm_kernel   <<<UBLKS, 256, 0, stream>>>(x, wA, wB0, wB1, wC0, wC1, U8, S8);
    final_T_kernel <<<25,   512, 0, stream>>>(x, U8, S8, W1, b1, T, out);
    final_out_kernel<<<5,   512, 0, stream>>>(T, W2, b2, out);
}